// Round 6
// baseline (575.690 us; speedup 1.0000x reference)
//
#include <hip/hip_runtime.h>

#define NN 100000
#define NE 1600000
#define DIM 128
#define NT 13            // src tiles: src>>13 -> 8192 rows = 2 MB bf16 per tile
#define SH 13
#define LEN (NN * NT)    // buckets, row-major: idx = (dst>>3)*104 + (dst&7)*13 + tile
#define NB_SCAN ((LEN + 1023) / 1024)
#define FST 140          // smF row stride (dwords): 16B-aligned
#define NGRP 12500       // rowgroups (NN/8)
#define PW 4             // dst-window passes in k_scat (window ~2.9MB fits 4MB L2)
#define GW ((NGRP + PW - 1) / PW)
#define CH 8             // gather chunk: edges per LDS-DMA batch

typedef __attribute__((ext_vector_type(8))) short short8;
typedef __attribute__((ext_vector_type(4))) float f4;
typedef __attribute__((ext_vector_type(2))) float f2;
typedef __attribute__((ext_vector_type(4))) unsigned u4;

__device__ __forceinline__ unsigned short f2bf(float f){
  unsigned x = __float_as_uint(f);
  x += 0x7fffu + ((x >> 16) & 1u);
  return (unsigned short)(x >> 16);
}
__device__ __forceinline__ unsigned pack2(float lo, float hi){
  return ((unsigned)f2bf(hi) << 16) | (unsigned)f2bf(lo);
}
__device__ __forceinline__ float blo(unsigned u){ return __uint_as_float(u << 16); }
__device__ __forceinline__ float bhi(unsigned u){ return __uint_as_float(u & 0xffff0000u); }
__device__ __forceinline__ short8 cvt8(f4 a, f4 b){
  short8 r;
  #pragma unroll
  for (int j = 0; j < 4; ++j){ r[j] = (short)f2bf(a[j]); r[j+4] = (short)f2bf(b[j]); }
  return r;
}

// async global->LDS DMA: per-lane global src, wave-uniform LDS base + lane*4
__device__ __forceinline__ void gl_lds(const unsigned* g, unsigned* l){
  __builtin_amdgcn_global_load_lds(
      (const __attribute__((address_space(1))) unsigned*)g,
      (__attribute__((address_space(3))) unsigned*)l,
      4, 0, 0);
}

// ---------------- fallback sentinel ----------------
__global__ void k_sentinel(float* __restrict__ out, int n){
  int i = blockIdx.x * blockDim.x + threadIdx.x;
  if (i < n) out[i] = 12345.0f;
}

// ---------------- fused: x fp32 -> bf16x2  +  histogram ----------------
__global__ void k_cvthist(const float* __restrict__ x, unsigned* __restrict__ xb,
                          const int* __restrict__ src, const int* __restrict__ dst,
                          int* __restrict__ cnt){
  int i = blockIdx.x * blockDim.x + threadIdx.x;
  if (i < NN * 16){
    f4 a = ((const f4*)x)[2 * i];
    f4 b = ((const f4*)x)[2 * i + 1];
    u4 o;
    o[0] = pack2(a[0], a[1]); o[1] = pack2(a[2], a[3]);
    o[2] = pack2(b[0], b[1]); o[3] = pack2(b[2], b[3]);
    ((u4*)xb)[i] = o;
  }
  if (i < NE){
    int s = src[i], d = dst[i];
    atomicAdd(&cnt[(d >> 3) * 104 + (d & 7) * 13 + (s >> SH)], 1);
  }
}

__global__ void k_bsum(const int* __restrict__ cnt, int* __restrict__ bsum, int len){
  __shared__ int sh[256];
  int t = threadIdx.x, b = blockIdx.x;
  int base = b * 1024 + t * 4;
  int s = 0;
  #pragma unroll
  for (int j = 0; j < 4; ++j){ int i = base + j; if (i < len) s += cnt[i]; }
  sh[t] = s; __syncthreads();
  for (int off = 128; off > 0; off >>= 1){
    if (t < off) sh[t] += sh[t + off];
    __syncthreads();
  }
  if (t == 0) bsum[b] = sh[0];
}

__global__ void k_scanp(const int* __restrict__ bsum, int* __restrict__ boff, int nb){
  __shared__ int sh[256];
  int t = threadIdx.x;
  int chunk = (nb + 255) / 256;
  int s = 0;
  for (int j = 0; j < chunk; ++j){ int i = t * chunk + j; if (i < nb) s += bsum[i]; }
  sh[t] = s; __syncthreads();
  int tin = s;
  for (int off = 1; off < 256; off <<= 1){
    int u = (t >= off) ? sh[t - off] : 0;
    __syncthreads();
    sh[t] += u;
    __syncthreads();
  }
  int run = sh[t] - tin;
  for (int j = 0; j < chunk; ++j){
    int i = t * chunk + j;
    if (i < nb){ boff[i] = run; run += bsum[i]; }
  }
}

__global__ void k_scanf(const int* __restrict__ cnt, const int* __restrict__ boff,
                        int* __restrict__ rp, int* __restrict__ pos, int len){
  __shared__ int sh[256];
  int t = threadIdx.x, b = blockIdx.x;
  int base = b * 1024 + t * 4;
  int c[4]; int s = 0;
  #pragma unroll
  for (int j = 0; j < 4; ++j){ int i = base + j; c[j] = (i < len) ? cnt[i] : 0; s += c[j]; }
  sh[t] = s; __syncthreads();
  int tin = s;
  for (int off = 1; off < 256; off <<= 1){
    int u = (t >= off) ? sh[t - off] : 0;
    __syncthreads();
    sh[t] += u;
    __syncthreads();
  }
  int run = boff[b] + sh[t] - tin;
  #pragma unroll
  for (int j = 0; j < 4; ++j){
    int i = base + j;
    if (i < len){
      rp[i] = run; pos[i] = run; run += c[j];
      if (i == len - 1) rp[len] = run;
    }
  }
}

// ---------------- direct dst-windowed scatter to ss32 -------------------------
__global__ __launch_bounds__(256)
void k_scat(const int* __restrict__ src, const int* __restrict__ dst,
            int* __restrict__ pos, unsigned* __restrict__ ss32){
  int tid = blockIdx.x * 256 + threadIdx.x;
  int stride = gridDim.x * 256;
  for (int p = 0; p < PW; ++p){
    int glo = p * GW, ghi = glo + GW;
    for (int i = tid; i < NE; i += stride){
      int d = dst[i];
      int g = d >> 3;
      if (g >= glo && g < ghi){
        int s = src[i];
        int b = g * 104 + (d & 7) * 13 + (s >> SH);
        int q = atomicAdd(&pos[b], 1);
        ss32[q] = (unsigned)s;
      }
    }
  }
}

// ---------------- W packing ----------------
template<int NB16>
__global__ void k_pack(const float* __restrict__ Wl,
                       const float* __restrict__ Wr,
                       unsigned short* __restrict__ Bp){
  constexpr int DOUT = NB16 * 16;
  int idx = blockIdx.x * blockDim.x + threadIdx.x;
  if (idx >= 8 * NB16 * 64) return;
  int lane = idx & 63;
  int nb = (idx >> 6) % NB16;
  int ks = idx / (64 * NB16);
  int n = nb * 16 + (lane & 15);
  int k0 = ks * 32 + (lane >> 4) * 8;
  short8 v;
  #pragma unroll
  for (int j = 0; j < 8; ++j){
    int k = k0 + j;
    float w = (k < 128) ? Wl[k * DOUT + n] : Wr[(k - 128) * DOUT + n];
    v[j] = (short)f2bf(w);
  }
  ((short8*)Bp)[idx] = v;
}

// ---------------- fused tiled mean-aggregate + dual-GEMM (+BN+ReLU) ----------
// Gather via global_load_lds LDS-DMA: zero destination VGPRs per request, so
// each wave sustains 8-16 outstanding 256B row-fetches (double-buffered CH=8
// staging) instead of the 4-8 VGPR-bound loads of R0-R5 (all stuck at ~79us,
// ~5 TB/s delivered -> concurrency-limited hypothesis). The rfl of the next
// chunk's records gives the in-order vmcnt drain of the previous chunk's DMAs;
// explicit vmcnt(0)+sched_barrier guards the epilogue (rule-18 discipline).
// Row tracking is scalar (row-major stream, ~16 edges/row, uniform branch);
// consume is ds_read_b32 + 2 adds per edge.
template<int NB16, bool DO_BN>
__global__ __launch_bounds__(256, 4)
void k_fused(const unsigned* __restrict__ Xb,
             const int* __restrict__ rp2, const unsigned* __restrict__ ss32,
             const unsigned short* __restrict__ Bp,
             const float* __restrict__ bias,
             const float* __restrict__ bg, const float* __restrict__ bb,
             const float* __restrict__ bm, const float* __restrict__ bv,
             unsigned short* __restrict__ OutB, float* __restrict__ OutF){
  constexpr int DOUT = NB16 * 16;
  constexpr int NBW = NB16 / 4;
  __shared__ float smF[32][FST];
  __shared__ unsigned stg[4][2][CH][64];   // per-wave double-buffered staging
  const int t = threadIdx.x;
  const int lane = t & 63;
  const int wv = t >> 6;
  const int m0 = blockIdx.x * 32;
  const int g = blockIdx.x * 4 + wv;      // rowgroup owned by this wave

  float* const base = &smF[wv * 8][0];
  const unsigned* const Xu = Xb;

  // prefetch the 9 row bounds for this wave's rowgroup
  int bnd = (lane < 9) ? rp2[g * 104 + lane * 13] : 0;
  int e         = __builtin_amdgcn_readfirstlane(__shfl(bnd, 0));
  const int end = __builtin_amdgcn_readfirstlane(__shfl(bnd, 8));
  int tt = 0;
  int nb = __builtin_amdgcn_readfirstlane(__shfl(bnd, 1));
  float ax = 0.f, ay = 0.f;

  unsigned sc[CH];
  #define RFL8(QA,QB) { \
    sc[0]=(unsigned)__builtin_amdgcn_readfirstlane((int)(QA)[0]); \
    sc[1]=(unsigned)__builtin_amdgcn_readfirstlane((int)(QA)[1]); \
    sc[2]=(unsigned)__builtin_amdgcn_readfirstlane((int)(QA)[2]); \
    sc[3]=(unsigned)__builtin_amdgcn_readfirstlane((int)(QA)[3]); \
    sc[4]=(unsigned)__builtin_amdgcn_readfirstlane((int)(QB)[0]); \
    sc[5]=(unsigned)__builtin_amdgcn_readfirstlane((int)(QB)[1]); \
    sc[6]=(unsigned)__builtin_amdgcn_readfirstlane((int)(QB)[2]); \
    sc[7]=(unsigned)__builtin_amdgcn_readfirstlane((int)(QB)[3]); }

  #define CONSUME(BUF, PN, EP) { \
    for (int i = 0; i < (PN); ++i){ \
      int ei = (EP) + i; \
      while (ei >= nb){ \
        float* p = base + tt * FST + 2 * lane; p[0] = ax; p[1] = ay; \
        ax = 0.f; ay = 0.f; ++tt; \
        nb = __builtin_amdgcn_readfirstlane(__shfl(bnd, tt + 1)); \
      } \
      unsigned u = stg[wv][BUF][i][lane]; \
      ax += blo(u); ay += bhi(u); \
    } }

  if (e < end){
    int buf = 0;
    int n = end - e; if (n > CH) n = CH;
    u4 qa = *(const u4*)(ss32 + e);
    u4 qb = *(const u4*)(ss32 + e + 4);
    RFL8(qa, qb);
    for (int i = 0; i < n; ++i)
      gl_lds(Xu + (size_t)sc[i] * 64 + lane, &stg[wv][0][i][0]);
    int ep = e, pn = n;
    e += n;
    while (e < end){
      int n2 = end - e; if (n2 > CH) n2 = CH;
      u4 qa2 = *(const u4*)(ss32 + e);
      u4 qb2 = *(const u4*)(ss32 + e + 4);
      RFL8(qa2, qb2);                      // rfl wait drains prev chunk's DMAs
      __builtin_amdgcn_sched_barrier(0);
      int nbuf = buf ^ 1;
      for (int i = 0; i < n2; ++i)
        gl_lds(Xu + (size_t)sc[i] * 64 + lane, &stg[wv][nbuf][i][0]);
      __builtin_amdgcn_sched_barrier(0);
      CONSUME(buf, pn, ep);
      ep = e; pn = n2; e += n2; buf = nbuf;
    }
    asm volatile("s_waitcnt vmcnt(0)" ::: "memory");
    __builtin_amdgcn_sched_barrier(0);
    CONSUME(buf, pn, ep);
  }
  // flush current row; trailing rows (no edges) get zeros
  { float* p = base + tt * FST + 2 * lane; p[0] = ax; p[1] = ay; }
  for (int rr = tt + 1; rr < 8; ++rr){
    float* p = base + rr * FST + 2 * lane; p[0] = 0.f; p[1] = 0.f;
  }
  #undef RFL8
  #undef CONSUME
  __syncthreads();

  // normalize (degree = rp2 range width)
  {
    int row = t >> 3;                    // 0..31 within block
    int gg = blockIdx.x * 4 + (row >> 3);
    int rr = row & 7;
    int beg = rp2[gg * 104 + rr * 13];
    int fin = rp2[gg * 104 + rr * 13 + 13];
    int d = fin - beg;
    float inv = (d > 0) ? 1.f / (float)d : 0.f;
    float* pr = &smF[row][(t & 7) * 16];
    #pragma unroll
    for (int i = 0; i < 16; ++i) pr[i] *= inv;
  }
  __syncthreads();

  // ---- phase 2: dual GEMM ----
  const int q2 = lane >> 4, lr = lane & 15;
  const short8* pb = (const short8*)Bp + lane;
  f4 acc[2][NBW];
  #pragma unroll
  for (int gg = 0; gg < 2; ++gg)
    #pragma unroll
    for (int j = 0; j < NBW; ++j)
      acc[gg][j] = (f4){0.f, 0.f, 0.f, 0.f};

  #pragma unroll
  for (int ks = 0; ks < 4; ++ks){
    const float* r0 = &smF[lr][ks * 32 + q2 * 8];
    const float* r1 = &smF[lr + 16][ks * 32 + q2 * 8];
    short8 a0 = cvt8(*(const f4*)r0, *(const f4*)(r0 + 4));
    short8 a1 = cvt8(*(const f4*)r1, *(const f4*)(r1 + 4));
    #pragma unroll
    for (int j = 0; j < NBW; ++j){
      int nb2 = wv * NBW + j;
      short8 b = pb[(ks * NB16 + nb2) * 64];
      acc[0][j] = __builtin_amdgcn_mfma_f32_16x16x32_bf16(a0, b, acc[0][j], 0, 0, 0);
      acc[1][j] = __builtin_amdgcn_mfma_f32_16x16x32_bf16(a1, b, acc[1][j], 0, 0, 0);
    }
  }
  #pragma unroll
  for (int ks = 0; ks < 4; ++ks){
    short8 a0 = *(const short8*)(Xb + (size_t)(m0 + lr) * 64 + q2*4 + ks*16);
    short8 a1 = *(const short8*)(Xb + (size_t)(m0 + lr + 16) * 64 + q2*4 + ks*16);
    #pragma unroll
    for (int j = 0; j < NBW; ++j){
      int nb2 = wv * NBW + j;
      short8 b = pb[((4 + ks) * NB16 + nb2) * 64];
      acc[0][j] = __builtin_amdgcn_mfma_f32_16x16x32_bf16(a0, b, acc[0][j], 0, 0, 0);
      acc[1][j] = __builtin_amdgcn_mfma_f32_16x16x32_bf16(a1, b, acc[1][j], 0, 0, 0);
    }
  }

  // ---- epilogue ----
  #pragma unroll
  for (int j = 0; j < NBW; ++j){
    int col = (wv * NBW + j) * 16 + lr;
    float S = 1.f, T;
    if constexpr (DO_BN){
      float s = bg[col] * rsqrtf(bv[col] + 1e-5f);
      S = s;
      T = (bias[col] - bm[col]) * s + bb[col];
    } else {
      T = bias[col];
    }
    #pragma unroll
    for (int r = 0; r < 4; ++r){
      int row = m0 + q2 * 4 + r;
      float y0 = acc[0][j][r] * S + T;
      float y1 = acc[1][j][r] * S + T;
      if constexpr (DO_BN){
        y0 = y0 > 0.f ? y0 : 0.f;
        y1 = y1 > 0.f ? y1 : 0.f;
        OutB[(size_t)row * DOUT + col] = f2bf(y0);
        OutB[(size_t)(row + 16) * DOUT + col] = f2bf(y1);
      } else {
        OutF[(size_t)row * DOUT + col] = y0;
        OutF[(size_t)(row + 16) * DOUT + col] = y1;
      }
    }
  }
}

extern "C" void kernel_launch(void* const* d_in, const int* in_sizes, int n_in,
                              void* d_out, int out_size, void* d_ws, size_t ws_size,
                              hipStream_t stream){
  const float* x = (const float*)d_in[0];
  const int* ei = (const int*)d_in[1];
  const float* Wl0 = (const float*)d_in[2];
  const float* Wr0 = (const float*)d_in[3];
  const float* bl0 = (const float*)d_in[4];
  const float* Wl1 = (const float*)d_in[5];
  const float* Wr1 = (const float*)d_in[6];
  const float* bl1 = (const float*)d_in[7];
  const float* Wl2 = (const float*)d_in[8];
  const float* Wr2 = (const float*)d_in[9];
  const float* bl2 = (const float*)d_in[10];
  const float* g0 = (const float*)d_in[11];
  const float* b0 = (const float*)d_in[12];
  const float* bm0 = (const float*)d_in[13];
  const float* bv0 = (const float*)d_in[14];
  const float* g1 = (const float*)d_in[15];
  const float* b1 = (const float*)d_in[16];
  const float* bm1 = (const float*)d_in[17];
  const float* bv1 = (const float*)d_in[18];

  const size_t REQUIRED = 51600000;
  if (ws_size < REQUIRED){
    k_sentinel<<<(out_size + 255) / 256, 256, 0, stream>>>((float*)d_out, out_size);
    return;
  }

  char* w = (char*)d_ws;
  size_t off = 0;
  auto alloc = [&](size_t bytes) -> char* {
    char* p = w + off; off = (off + bytes + 255) & ~(size_t)255; return p;
  };
  int* rp2 = (int*)alloc((size_t)(LEN + 1) * 4);
  unsigned* ss32 = (unsigned*)alloc((size_t)NE * 4);
  unsigned short* bp0 = (unsigned short*)alloc(8 * 8 * 64 * 8 * 2);
  unsigned short* bp1 = (unsigned short*)alloc(8 * 8 * 64 * 8 * 2);
  unsigned short* bp2 = (unsigned short*)alloc(8 * 4 * 64 * 8 * 2);
  unsigned* xb = (unsigned*)alloc((size_t)NN * 64 * 4);   // bf16x2 x; reused as h2
  unsigned short* h2 = (unsigned short*)xb;
  int* cnt2 = (int*)alloc((size_t)LEN * 4);
  int* pos2 = (int*)alloc((size_t)LEN * 4);
  int* bsum = (int*)alloc(NB_SCAN * 4);
  int* boff = (int*)alloc(NB_SCAN * 4);
  unsigned short* h1 = (unsigned short*)d_out;            // 25.6 MB, exactly d_out

  const int* srcI = ei;
  const int* dstI = ei + NE;

  hipMemsetAsync(cnt2, 0, (size_t)LEN * 4, stream);
  k_cvthist<<<(NE + 255) / 256, 256, 0, stream>>>(x, xb, srcI, dstI, cnt2);
  k_bsum<<<NB_SCAN, 256, 0, stream>>>(cnt2, bsum, LEN);
  k_scanp<<<1, 256, 0, stream>>>(bsum, boff, NB_SCAN);
  k_scanf<<<NB_SCAN, 256, 0, stream>>>(cnt2, boff, rp2, pos2, LEN);
  k_scat<<<1024, 256, 0, stream>>>(srcI, dstI, pos2, ss32);
  k_pack<8><<<16, 256, 0, stream>>>(Wl0, Wr0, bp0);
  k_pack<8><<<16, 256, 0, stream>>>(Wl1, Wr1, bp1);
  k_pack<4><<<8, 256, 0, stream>>>(Wl2, Wr2, bp2);

  k_fused<8, true ><<<3125, 256, 0, stream>>>(xb, rp2, ss32, bp0,
      bl0, g0, b0, bm0, bv0, h1, nullptr);
  k_fused<8, true ><<<3125, 256, 0, stream>>>((const unsigned*)h1, rp2, ss32, bp1,
      bl1, g1, b1, bm1, bv1, h2, nullptr);
  k_fused<4, false><<<3125, 256, 0, stream>>>((const unsigned*)h2, rp2, ss32, bp2,
      bl2, nullptr, nullptr, nullptr, nullptr, nullptr, (float*)d_out);
}

// Round 7
// 538.826 us; speedup vs baseline: 1.0684x; 1.0684x over previous
//
#include <hip/hip_runtime.h>

#define NN 100000
#define NE 1600000
#define DIM 128
#define NT 13            // src tiles: src>>13 -> 8192 rows = 2 MB bf16 per tile
#define SH 13
#define LEN (NN * NT)    // buckets, row-major: idx = (dst>>3)*104 + (dst&7)*13 + tile
#define NB_SCAN ((LEN + 1023) / 1024)
#define FST 140          // smF row stride (dwords): 16B-aligned
#define NGRP 12500       // rowgroups (NN/8)
#define PW 2             // dst-window passes in k_scat
#define GW ((NGRP + PW - 1) / PW)

typedef __attribute__((ext_vector_type(8))) short short8;
typedef __attribute__((ext_vector_type(4))) float f4;
typedef __attribute__((ext_vector_type(2))) float f2;
typedef __attribute__((ext_vector_type(4))) unsigned u4;

__device__ __forceinline__ unsigned short f2bf(float f){
  unsigned x = __float_as_uint(f);
  x += 0x7fffu + ((x >> 16) & 1u);
  return (unsigned short)(x >> 16);
}
__device__ __forceinline__ unsigned pack2(float lo, float hi){
  return ((unsigned)f2bf(hi) << 16) | (unsigned)f2bf(lo);
}
__device__ __forceinline__ float blo(unsigned u){ return __uint_as_float(u << 16); }
__device__ __forceinline__ float bhi(unsigned u){ return __uint_as_float(u & 0xffff0000u); }
__device__ __forceinline__ short8 cvt8(f4 a, f4 b){
  short8 r;
  #pragma unroll
  for (int j = 0; j < 4; ++j){ r[j] = (short)f2bf(a[j]); r[j+4] = (short)f2bf(b[j]); }
  return r;
}

// ---------------- fallback sentinel ----------------
__global__ void k_sentinel(float* __restrict__ out, int n){
  int i = blockIdx.x * blockDim.x + threadIdx.x;
  if (i < n) out[i] = 12345.0f;
}

// ---------------- fused: x fp32 -> bf16x2  +  replicated histogram ----------
// Histogram atomics go to replica par(i) = (i>>8)&1  (== block parity ==
// XCD parity under round-robin dispatch): halves cross-XCD line ping-pong
// on the counter array. k_scat uses the SAME edge-parity for its cursor
// replica, so counts and placements match exactly.
__global__ void k_cvthist(const float* __restrict__ x, unsigned* __restrict__ xb,
                          const int* __restrict__ src, const int* __restrict__ dst,
                          int* __restrict__ cnt){
  int i = blockIdx.x * blockDim.x + threadIdx.x;
  if (i < NN * 16){
    f4 a = ((const f4*)x)[2 * i];
    f4 b = ((const f4*)x)[2 * i + 1];
    u4 o;
    o[0] = pack2(a[0], a[1]); o[1] = pack2(a[2], a[3]);
    o[2] = pack2(b[0], b[1]); o[3] = pack2(b[2], b[3]);
    ((u4*)xb)[i] = o;
  }
  if (i < NE){
    int s = src[i], d = dst[i];
    int par = (i >> 8) & 1;
    atomicAdd(&cnt[par * LEN + (d >> 3) * 104 + (d & 7) * 13 + (s >> SH)], 1);
  }
}

__global__ void k_bsum(const int* __restrict__ cnt, int* __restrict__ bsum, int len){
  __shared__ int sh[256];
  int t = threadIdx.x, b = blockIdx.x;
  int base = b * 1024 + t * 4;
  int s = 0;
  #pragma unroll
  for (int j = 0; j < 4; ++j){
    int i = base + j;
    if (i < len) s += cnt[i] + cnt[LEN + i];
  }
  sh[t] = s; __syncthreads();
  for (int off = 128; off > 0; off >>= 1){
    if (t < off) sh[t] += sh[t + off];
    __syncthreads();
  }
  if (t == 0) bsum[b] = sh[0];
}

__global__ void k_scanp(const int* __restrict__ bsum, int* __restrict__ boff, int nb){
  __shared__ int sh[256];
  int t = threadIdx.x;
  int chunk = (nb + 255) / 256;
  int s = 0;
  for (int j = 0; j < chunk; ++j){ int i = t * chunk + j; if (i < nb) s += bsum[i]; }
  sh[t] = s; __syncthreads();
  int tin = s;
  for (int off = 1; off < 256; off <<= 1){
    int u = (t >= off) ? sh[t - off] : 0;
    __syncthreads();
    sh[t] += u;
    __syncthreads();
  }
  int run = sh[t] - tin;
  for (int j = 0; j < chunk; ++j){
    int i = t * chunk + j;
    if (i < nb){ boff[i] = run; run += bsum[i]; }
  }
}

// scan merges the two replicas; writes rp (stable bounds for k_fused) and
// per-replica start cursors IN-PLACE into cnt (cntA <- start, cntB <- start+cA)
__global__ void k_scanf(int* __restrict__ cnt, const int* __restrict__ boff,
                        int* __restrict__ rp, int len){
  __shared__ int sh[256];
  int t = threadIdx.x, b = blockIdx.x;
  int base = b * 1024 + t * 4;
  int cA[4], cB[4]; int s = 0;
  #pragma unroll
  for (int j = 0; j < 4; ++j){
    int i = base + j;
    cA[j] = (i < len) ? cnt[i] : 0;
    cB[j] = (i < len) ? cnt[LEN + i] : 0;
    s += cA[j] + cB[j];
  }
  sh[t] = s; __syncthreads();
  int tin = s;
  for (int off = 1; off < 256; off <<= 1){
    int u = (t >= off) ? sh[t - off] : 0;
    __syncthreads();
    sh[t] += u;
    __syncthreads();
  }
  int run = boff[b] + sh[t] - tin;
  #pragma unroll
  for (int j = 0; j < 4; ++j){
    int i = base + j;
    if (i < len){
      rp[i] = run;
      cnt[i] = run;                  // posA
      cnt[LEN + i] = run + cA[j];    // posB
      run += cA[j] + cB[j];
      if (i == len - 1) rp[len] = run;
    }
  }
}

// ---------------- direct dst-windowed scatter to ss32 -------------------------
// Cursor replica by edge parity (== block parity; grid is even so the
// grid-stride preserves parity). A-class edges fill [start,start+cA),
// B-class [start+cA, start+cA+cB) -- bucket stays contiguous.
__global__ __launch_bounds__(256)
void k_scat(const int* __restrict__ src, const int* __restrict__ dst,
            int* __restrict__ pos, unsigned* __restrict__ ss32){
  int tid = blockIdx.x * 256 + threadIdx.x;
  int stride = gridDim.x * 256;
  int* mypos = pos + (blockIdx.x & 1) * LEN;
  for (int p = 0; p < PW; ++p){
    int glo = p * GW, ghi = glo + GW;
    for (int i = tid; i < NE; i += stride){
      int d = dst[i];
      int g = d >> 3;
      if (g >= glo && g < ghi){
        int s = src[i];
        int b = g * 104 + (d & 7) * 13 + (s >> SH);
        int q = atomicAdd(&mypos[b], 1);
        ss32[q] = (unsigned)s;
      }
    }
  }
}

// ---------------- W packing (all three layers in one launch) ----------------
template<int NB16>
__device__ __forceinline__ void packone(int idx, const float* __restrict__ Wl,
                                        const float* __restrict__ Wr,
                                        unsigned short* __restrict__ Bp){
  constexpr int DOUT = NB16 * 16;
  int lane = idx & 63;
  int nb = (idx >> 6) % NB16;
  int ks = idx / (64 * NB16);
  int n = nb * 16 + (lane & 15);
  int k0 = ks * 32 + (lane >> 4) * 8;
  short8 v;
  #pragma unroll
  for (int j = 0; j < 8; ++j){
    int k = k0 + j;
    float w = (k < 128) ? Wl[k * DOUT + n] : Wr[(k - 128) * DOUT + n];
    v[j] = (short)f2bf(w);
  }
  ((short8*)Bp)[idx] = v;
}

__global__ void k_packall(const float* __restrict__ Wl0, const float* __restrict__ Wr0,
                          const float* __restrict__ Wl1, const float* __restrict__ Wr1,
                          const float* __restrict__ Wl2, const float* __restrict__ Wr2,
                          unsigned short* __restrict__ bp0,
                          unsigned short* __restrict__ bp1,
                          unsigned short* __restrict__ bp2){
  int idx = blockIdx.x * blockDim.x + threadIdx.x;
  if (idx < 4096)       packone<8>(idx,        Wl0, Wr0, bp0);
  else if (idx < 8192)  packone<8>(idx - 4096, Wl1, Wr1, bp1);
  else if (idx < 10240) packone<4>(idx - 8192, Wl2, Wr2, bp2);
}

// ---------------- fused tiled mean-aggregate + dual-GEMM (+BN+ReLU) ----------
// R5's x4-wide gather (known-good 79us): global_load_dwordx4, 16 lanes cover
// one 256B row -> one VMEM instruction fetches 4 edges. Register accumulators,
// shfl_xor fold, zero per-edge LDS ops. Gather phase is at its per-CU
// line-throughput floor (R0-R6: six structures, all >=77us).
template<int NB16, bool DO_BN>
__global__ __launch_bounds__(256, 8)
void k_fused(const unsigned* __restrict__ Xb,
             const int* __restrict__ rp2, const unsigned* __restrict__ ss32,
             const unsigned short* __restrict__ Bp,
             const float* __restrict__ bias,
             const float* __restrict__ bg, const float* __restrict__ bb,
             const float* __restrict__ bm, const float* __restrict__ bv,
             unsigned short* __restrict__ OutB, float* __restrict__ OutF){
  constexpr int DOUT = NB16 * 16;
  constexpr int NBW = NB16 / 4;
  __shared__ float smF[32][FST];
  const int t = threadIdx.x;
  const int lane = t & 63;
  const int wv = t >> 6;
  const int m0 = blockIdx.x * 32;
  const int g = blockIdx.x * 4 + wv;      // rowgroup owned by this wave

  float* const base = &smF[wv * 8][0];
  const char* const Xc = (const char*)Xb;
  const int q = lane >> 4;                // 16-lane group id (0..3)
  const int li = lane & 15;
  const unsigned li16 = (unsigned)li * 16u;

  // prefetch the 9 row bounds for this wave's rowgroup
  int bnd = (lane < 9) ? rp2[g * 104 + lane * 13] : 0;

  #define LD4(r) (*(const u4*)(Xc + ((size_t)(r) << 8) + li16))
  #define ACC(v) { a0 += blo((v)[0]); a1 += bhi((v)[0]); a2 += blo((v)[1]); a3 += bhi((v)[1]); \
                   a4 += blo((v)[2]); a5 += bhi((v)[2]); a6 += blo((v)[3]); a7 += bhi((v)[3]); }

  #pragma unroll 1
  for (int r = 0; r < 8; ++r){
    int e   = __builtin_amdgcn_readfirstlane(__shfl(bnd, r));
    int end = __builtin_amdgcn_readfirstlane(__shfl(bnd, r + 1));
    float a0 = 0.f, a1 = 0.f, a2 = 0.f, a3 = 0.f;
    float a4 = 0.f, a5 = 0.f, a6 = 0.f, a7 = 0.f;
    // 16 edges per iter: 4 rec loads + 4 x4-gathers in flight
    while (e + 16 <= end){
      unsigned r0 = ss32[e + q];
      unsigned r1 = ss32[e + 4 + q];
      unsigned r2 = ss32[e + 8 + q];
      unsigned r3 = ss32[e + 12 + q];
      u4 v0 = LD4(r0);
      u4 v1 = LD4(r1);
      u4 v2 = LD4(r2);
      u4 v3 = LD4(r3);
      ACC(v0); ACC(v1); ACC(v2); ACC(v3);
      e += 16;
    }
    if (e + 8 <= end){
      unsigned r0 = ss32[e + q];
      unsigned r1 = ss32[e + 4 + q];
      u4 v0 = LD4(r0);
      u4 v1 = LD4(r1);
      ACC(v0); ACC(v1);
      e += 8;
    }
    // predicated tail: 1..7 edges, 4 at a time with clamp+mask
    while (e < end){
      int nv = end - e;                       // scalar
      int sel = (q < nv) ? q : (nv - 1);
      unsigned rr = ss32[e + sel];
      u4 v = LD4(rr);
      if (q >= nv){ v[0] = 0; v[1] = 0; v[2] = 0; v[3] = 0; }
      ACC(v);
      e += (nv < 4) ? nv : 4;
    }
    // fold the 4 group partials (lanes l, l+16, l+32, l+48 hold same dims)
    a0 += __shfl_xor(a0, 16); a1 += __shfl_xor(a1, 16);
    a2 += __shfl_xor(a2, 16); a3 += __shfl_xor(a3, 16);
    a4 += __shfl_xor(a4, 16); a5 += __shfl_xor(a5, 16);
    a6 += __shfl_xor(a6, 16); a7 += __shfl_xor(a7, 16);
    a0 += __shfl_xor(a0, 32); a1 += __shfl_xor(a1, 32);
    a2 += __shfl_xor(a2, 32); a3 += __shfl_xor(a3, 32);
    a4 += __shfl_xor(a4, 32); a5 += __shfl_xor(a5, 32);
    a6 += __shfl_xor(a6, 32); a7 += __shfl_xor(a7, 32);
    if (q == 0){
      float* p = base + r * FST + li * 8;
      f4 w0; w0[0] = a0; w0[1] = a1; w0[2] = a2; w0[3] = a3;
      f4 w1; w1[0] = a4; w1[1] = a5; w1[2] = a6; w1[3] = a7;
      *(f4*)p = w0;
      *(f4*)(p + 4) = w1;
    }
  }
  #undef LD4
  #undef ACC
  __syncthreads();

  // normalize (degree = rp2 range width)
  {
    int row = t >> 3;                    // 0..31 within block
    int gg = blockIdx.x * 4 + (row >> 3);
    int rr = row & 7;
    int beg = rp2[gg * 104 + rr * 13];
    int fin = rp2[gg * 104 + rr * 13 + 13];
    int d = fin - beg;
    float inv = (d > 0) ? 1.f / (float)d : 0.f;
    float* pr = &smF[row][(t & 7) * 16];
    #pragma unroll
    for (int i = 0; i < 16; ++i) pr[i] *= inv;
  }
  __syncthreads();

  // ---- phase 2: dual GEMM ----
  const int q2 = lane >> 4, lr = lane & 15;
  const short8* pb = (const short8*)Bp + lane;
  f4 acc[2][NBW];
  #pragma unroll
  for (int gg = 0; gg < 2; ++gg)
    #pragma unroll
    for (int j = 0; j < NBW; ++j)
      acc[gg][j] = (f4){0.f, 0.f, 0.f, 0.f};

  #pragma unroll
  for (int ks = 0; ks < 4; ++ks){
    const float* r0 = &smF[lr][ks * 32 + q2 * 8];
    const float* r1 = &smF[lr + 16][ks * 32 + q2 * 8];
    short8 a0 = cvt8(*(const f4*)r0, *(const f4*)(r0 + 4));
    short8 a1 = cvt8(*(const f4*)r1, *(const f4*)(r1 + 4));
    #pragma unroll
    for (int j = 0; j < NBW; ++j){
      int nb2 = wv * NBW + j;
      short8 b = pb[(ks * NB16 + nb2) * 64];
      acc[0][j] = __builtin_amdgcn_mfma_f32_16x16x32_bf16(a0, b, acc[0][j], 0, 0, 0);
      acc[1][j] = __builtin_amdgcn_mfma_f32_16x16x32_bf16(a1, b, acc[1][j], 0, 0, 0);
    }
  }
  #pragma unroll
  for (int ks = 0; ks < 4; ++ks){
    short8 a0 = *(const short8*)(Xb + (size_t)(m0 + lr) * 64 + q2*4 + ks*16);
    short8 a1 = *(const short8*)(Xb + (size_t)(m0 + lr + 16) * 64 + q2*4 + ks*16);
    #pragma unroll
    for (int j = 0; j < NBW; ++j){
      int nb2 = wv * NBW + j;
      short8 b = pb[((4 + ks) * NB16 + nb2) * 64];
      acc[0][j] = __builtin_amdgcn_mfma_f32_16x16x32_bf16(a0, b, acc[0][j], 0, 0, 0);
      acc[1][j] = __builtin_amdgcn_mfma_f32_16x16x32_bf16(a1, b, acc[1][j], 0, 0, 0);
    }
  }

  // ---- epilogue ----
  #pragma unroll
  for (int j = 0; j < NBW; ++j){
    int col = (wv * NBW + j) * 16 + lr;
    float S = 1.f, T;
    if constexpr (DO_BN){
      float s = bg[col] * rsqrtf(bv[col] + 1e-5f);
      S = s;
      T = (bias[col] - bm[col]) * s + bb[col];
    } else {
      T = bias[col];
    }
    #pragma unroll
    for (int r = 0; r < 4; ++r){
      int row = m0 + q2 * 4 + r;
      float y0 = acc[0][j][r] * S + T;
      float y1 = acc[1][j][r] * S + T;
      if constexpr (DO_BN){
        y0 = y0 > 0.f ? y0 : 0.f;
        y1 = y1 > 0.f ? y1 : 0.f;
        OutB[(size_t)row * DOUT + col] = f2bf(y0);
        OutB[(size_t)(row + 16) * DOUT + col] = f2bf(y1);
      } else {
        OutF[(size_t)row * DOUT + col] = y0;
        OutF[(size_t)(row + 16) * DOUT + col] = y1;
      }
    }
  }
}

extern "C" void kernel_launch(void* const* d_in, const int* in_sizes, int n_in,
                              void* d_out, int out_size, void* d_ws, size_t ws_size,
                              hipStream_t stream){
  const float* x = (const float*)d_in[0];
  const int* ei = (const int*)d_in[1];
  const float* Wl0 = (const float*)d_in[2];
  const float* Wr0 = (const float*)d_in[3];
  const float* bl0 = (const float*)d_in[4];
  const float* Wl1 = (const float*)d_in[5];
  const float* Wr1 = (const float*)d_in[6];
  const float* bl1 = (const float*)d_in[7];
  const float* Wl2 = (const float*)d_in[8];
  const float* Wr2 = (const float*)d_in[9];
  const float* bl2 = (const float*)d_in[10];
  const float* g0 = (const float*)d_in[11];
  const float* b0 = (const float*)d_in[12];
  const float* bm0 = (const float*)d_in[13];
  const float* bv0 = (const float*)d_in[14];
  const float* g1 = (const float*)d_in[15];
  const float* b1 = (const float*)d_in[16];
  const float* bm1 = (const float*)d_in[17];
  const float* bv1 = (const float*)d_in[18];

  const size_t REQUIRED = 51600000;
  if (ws_size < REQUIRED){
    k_sentinel<<<(out_size + 255) / 256, 256, 0, stream>>>((float*)d_out, out_size);
    return;
  }

  char* w = (char*)d_ws;
  size_t off = 0;
  auto alloc = [&](size_t bytes) -> char* {
    char* p = w + off; off = (off + bytes + 255) & ~(size_t)255; return p;
  };
  int* rp2 = (int*)alloc((size_t)(LEN + 1) * 4);
  unsigned* ss32 = (unsigned*)alloc((size_t)NE * 4);
  unsigned short* bp0 = (unsigned short*)alloc(8 * 8 * 64 * 8 * 2);
  unsigned short* bp1 = (unsigned short*)alloc(8 * 8 * 64 * 8 * 2);
  unsigned short* bp2 = (unsigned short*)alloc(8 * 4 * 64 * 8 * 2);
  unsigned* xb = (unsigned*)alloc((size_t)NN * 64 * 4);   // bf16x2 x; reused as h2
  unsigned short* h2 = (unsigned short*)xb;
  int* cnt2 = (int*)alloc((size_t)LEN * 2 * 4);           // 2 replicas; reused as pos
  int* bsum = (int*)alloc(NB_SCAN * 4);
  int* boff = (int*)alloc(NB_SCAN * 4);
  unsigned short* h1 = (unsigned short*)d_out;            // 25.6 MB, exactly d_out

  const int* srcI = ei;
  const int* dstI = ei + NE;

  hipMemsetAsync(cnt2, 0, (size_t)LEN * 2 * 4, stream);
  k_cvthist<<<(NE + 255) / 256, 256, 0, stream>>>(x, xb, srcI, dstI, cnt2);
  k_bsum<<<NB_SCAN, 256, 0, stream>>>(cnt2, bsum, LEN);
  k_scanp<<<1, 256, 0, stream>>>(bsum, boff, NB_SCAN);
  k_scanf<<<NB_SCAN, 256, 0, stream>>>(cnt2, boff, rp2, LEN);
  k_scat<<<1024, 256, 0, stream>>>(srcI, dstI, cnt2, ss32);
  k_packall<<<40, 256, 0, stream>>>(Wl0, Wr0, Wl1, Wr1, Wl2, Wr2, bp0, bp1, bp2);

  k_fused<8, true ><<<3125, 256, 0, stream>>>(xb, rp2, ss32, bp0,
      bl0, g0, b0, bm0, bv0, h1, nullptr);
  k_fused<8, true ><<<3125, 256, 0, stream>>>((const unsigned*)h1, rp2, ss32, bp1,
      bl1, g1, b1, bm1, bv1, h2, nullptr);
  k_fused<4, false><<<3125, 256, 0, stream>>>((const unsigned*)h2, rp2, ss32, bp2,
      bl2, nullptr, nullptr, nullptr, nullptr, nullptr, (float*)d_out);
}

// Round 8
// 422.800 us; speedup vs baseline: 1.3616x; 1.2744x over previous
//
#include <hip/hip_runtime.h>

#define NN 100000
#define NE 1600000
#define DIM 128
#define FST 140          // smF row stride (dwords): 16B-aligned
#define NGB 3125         // sort buckets = dst>>5 == k_fused block id (NN = 3125*32)
#define NBH 256          // histogram/scatter blocks
#define EPB (NE / NBH)   // 6250 edges per hist/scat block (exact)
#define LEN2 (NGB * NBH) // 800000 scan entries
#define NB_SCAN2 ((LEN2 + 1023) / 1024)

typedef __attribute__((ext_vector_type(8))) short short8;
typedef __attribute__((ext_vector_type(4))) float f4;
typedef __attribute__((ext_vector_type(4))) unsigned u4;

__device__ __forceinline__ unsigned short f2bf(float f){
  unsigned x = __float_as_uint(f);
  x += 0x7fffu + ((x >> 16) & 1u);
  return (unsigned short)(x >> 16);
}
__device__ __forceinline__ unsigned pack2(float lo, float hi){
  return ((unsigned)f2bf(hi) << 16) | (unsigned)f2bf(lo);
}
__device__ __forceinline__ float blo(unsigned u){ return __uint_as_float(u << 16); }
__device__ __forceinline__ float bhi(unsigned u){ return __uint_as_float(u & 0xffff0000u); }
__device__ __forceinline__ short8 cvt8(f4 a, f4 b){
  short8 r;
  #pragma unroll
  for (int j = 0; j < 4; ++j){ r[j] = (short)f2bf(a[j]); r[j+4] = (short)f2bf(b[j]); }
  return r;
}

// ---------------- fallback sentinel ----------------
__global__ void k_sentinel(float* __restrict__ out, int n){
  int i = blockIdx.x * blockDim.x + threadIdx.x;
  if (i < n) out[i] = 12345.0f;
}

// ---------------- x fp32 -> bf16x2 (pure; global-atomic histogram deleted) ---
__global__ void k_cvt(const float* __restrict__ x, unsigned* __restrict__ xb){
  int i = blockIdx.x * blockDim.x + threadIdx.x;   // i < NN*16
  if (i >= NN * 16) return;
  f4 a = ((const f4*)x)[2 * i];
  f4 b = ((const f4*)x)[2 * i + 1];
  u4 o;
  o[0] = pack2(a[0], a[1]); o[1] = pack2(a[2], a[3]);
  o[2] = pack2(b[0], b[1]); o[3] = pack2(b[2], b[3]);
  ((u4*)xb)[i] = o;
}

// ---------------- LDS histogram over 3125 buckets (NO global atomics) --------
// R7 evidence: 1.6M global atomicAdds = 102 MB of HBM write-through (64B/op),
// ~100us per atomic pass. LDS atomics + plain writes replace them entirely.
__global__ __launch_bounds__(256)
void k_hist(const int* __restrict__ dst, int* __restrict__ histT){
  __shared__ int h[NGB];
  int t = threadIdx.x, b = blockIdx.x;
  for (int i = t; i < NGB; i += 256) h[i] = 0;
  __syncthreads();
  int e0 = b * EPB;
  for (int i = t; i < EPB; i += 256)
    atomicAdd(&h[dst[e0 + i] >> 5], 1);
  __syncthreads();
  for (int i = t; i < NGB; i += 256) histT[i * NBH + b] = h[i];
}

__global__ void k_bsum(const int* __restrict__ cnt, int* __restrict__ bsum, int len){
  __shared__ int sh[256];
  int t = threadIdx.x, b = blockIdx.x;
  int base = b * 1024 + t * 4;
  int s = 0;
  #pragma unroll
  for (int j = 0; j < 4; ++j){ int i = base + j; if (i < len) s += cnt[i]; }
  sh[t] = s; __syncthreads();
  for (int off = 128; off > 0; off >>= 1){
    if (t < off) sh[t] += sh[t + off];
    __syncthreads();
  }
  if (t == 0) bsum[b] = sh[0];
}

__global__ void k_scanp(const int* __restrict__ bsum, int* __restrict__ boff, int nb){
  __shared__ int sh[256];
  int t = threadIdx.x;
  int chunk = (nb + 255) / 256;
  int s = 0;
  for (int j = 0; j < chunk; ++j){ int i = t * chunk + j; if (i < nb) s += bsum[i]; }
  sh[t] = s; __syncthreads();
  int tin = s;
  for (int off = 1; off < 256; off <<= 1){
    int u = (t >= off) ? sh[t - off] : 0;
    __syncthreads();
    sh[t] += u;
    __syncthreads();
  }
  int run = sh[t] - tin;
  for (int j = 0; j < chunk; ++j){
    int i = t * chunk + j;
    if (i < nb){ boff[i] = run; run += bsum[i]; }
  }
}

// scan histT in place to per-(bucket,block) bases; extract bucket bases Bb[]
__global__ void k_scanf2(int* __restrict__ hist, const int* __restrict__ boff,
                         int* __restrict__ Bb, int len){
  __shared__ int sh[256];
  int t = threadIdx.x, b = blockIdx.x;
  int base = b * 1024 + t * 4;
  int c[4]; int s = 0;
  #pragma unroll
  for (int j = 0; j < 4; ++j){ int i = base + j; c[j] = (i < len) ? hist[i] : 0; s += c[j]; }
  sh[t] = s; __syncthreads();
  int tin = s;
  for (int off = 1; off < 256; off <<= 1){
    int u = (t >= off) ? sh[t - off] : 0;
    __syncthreads();
    sh[t] += u;
    __syncthreads();
  }
  int run = boff[b] + sh[t] - tin;
  #pragma unroll
  for (int j = 0; j < 4; ++j){
    int i = base + j;
    if (i < len){
      if ((i & (NBH - 1)) == 0) Bb[i >> 8] = run;
      hist[i] = run;
      run += c[j];
      if (i == len - 1) Bb[NGB] = run;
    }
  }
}

// ---------------- scatter via LDS cursors (NO global atomics) ----------------
// payload = (src<<5) | (dst&31); slot from LDS atomicAdd on preloaded bases.
__global__ __launch_bounds__(256)
void k_scat(const int* __restrict__ src, const int* __restrict__ dst,
            const int* __restrict__ histT, unsigned* __restrict__ ss32){
  __shared__ int cur[NGB];
  int t = threadIdx.x, b = blockIdx.x;
  for (int i = t; i < NGB; i += 256) cur[i] = histT[i * NBH + b];
  __syncthreads();
  int e0 = b * EPB;
  for (int i = t; i < EPB; i += 256){
    int d = dst[e0 + i];
    int s = src[e0 + i];
    int slot = atomicAdd(&cur[d >> 5], 1);
    ss32[slot] = ((unsigned)s << 5) | (unsigned)(d & 31);
  }
}

// ---------------- per-bucket in-place row sort + row bounds ------------------
// Block b owns ss32[Bb[b],Bb[b+1]) (~512 edges, max ~640 for uniform dst;
// eb sized 1024 = >20 sigma margin). Sorts payloads by row (dst&31) in LDS,
// writes back contiguously as plain src, emits rowoffG[b*33 + r].
__global__ __launch_bounds__(256)
void k_scat2(unsigned* __restrict__ ss32, const int* __restrict__ Bb,
             int* __restrict__ rowoffG){
  __shared__ unsigned eb[1024];
  __shared__ int rc[32];
  __shared__ int ro[33];
  int t = threadIdx.x, b = blockIdx.x;
  int b0 = Bb[b], b1 = Bb[b + 1];
  int ne = b1 - b0;
  if (t < 32) rc[t] = 0;
  __syncthreads();
  unsigned pl[4];
  {
    int k = 0;
    for (int i = t; i < ne; i += 256, ++k){
      unsigned p = ss32[b0 + i];
      pl[k & 3] = p;
      atomicAdd(&rc[p & 31u], 1);
    }
  }
  __syncthreads();
  if (t == 0){
    int run = 0;
    #pragma unroll
    for (int r = 0; r < 32; ++r){ ro[r] = run; run += rc[r]; }
    ro[32] = run;
  }
  __syncthreads();
  if (t < 33) rowoffG[b * 33 + t] = b0 + ro[t];
  if (t < 32) rc[t] = ro[t];          // running cursors
  __syncthreads();
  {
    int k = 0;
    for (int i = t; i < ne; i += 256, ++k){
      unsigned p = pl[k & 3];
      int slot = atomicAdd(&rc[p & 31u], 1);
      if (slot < 1024) eb[slot] = p >> 5;   // plain src
    }
  }
  __syncthreads();
  for (int i = t; i < ne; i += 256) ss32[b0 + i] = eb[i];
}

// ---------------- W packing (all three layers in one launch) ----------------
template<int NB16>
__device__ __forceinline__ void packone(int idx, const float* __restrict__ Wl,
                                        const float* __restrict__ Wr,
                                        unsigned short* __restrict__ Bp){
  constexpr int DOUT = NB16 * 16;
  int lane = idx & 63;
  int nb = (idx >> 6) % NB16;
  int ks = idx / (64 * NB16);
  int n = nb * 16 + (lane & 15);
  int k0 = ks * 32 + (lane >> 4) * 8;
  short8 v;
  #pragma unroll
  for (int j = 0; j < 8; ++j){
    int k = k0 + j;
    float w = (k < 128) ? Wl[k * DOUT + n] : Wr[(k - 128) * DOUT + n];
    v[j] = (short)f2bf(w);
  }
  ((short8*)Bp)[idx] = v;
}

__global__ void k_packall(const float* __restrict__ Wl0, const float* __restrict__ Wr0,
                          const float* __restrict__ Wl1, const float* __restrict__ Wr1,
                          const float* __restrict__ Wl2, const float* __restrict__ Wr2,
                          unsigned short* __restrict__ bp0,
                          unsigned short* __restrict__ bp1,
                          unsigned short* __restrict__ bp2){
  int idx = blockIdx.x * blockDim.x + threadIdx.x;
  if (idx < 4096)       packone<8>(idx,        Wl0, Wr0, bp0);
  else if (idx < 8192)  packone<8>(idx - 4096, Wl1, Wr1, bp1);
  else if (idx < 10240) packone<4>(idx - 8192, Wl2, Wr2, bp2);
}

// ---------------- fused tiled mean-aggregate + dual-GEMM (+BN+ReLU) ----------
// R5's proven x4-wide gather body; only the bounds source changed (rowoffG
// written by k_scat2) and records are plain src indices.
template<int NB16, bool DO_BN>
__global__ __launch_bounds__(256, 8)
void k_fused(const unsigned* __restrict__ Xb,
             const int* __restrict__ rowoffG, const unsigned* __restrict__ ss32,
             const unsigned short* __restrict__ Bp,
             const float* __restrict__ bias,
             const float* __restrict__ bg, const float* __restrict__ bb,
             const float* __restrict__ bm, const float* __restrict__ bv,
             unsigned short* __restrict__ OutB, float* __restrict__ OutF){
  constexpr int DOUT = NB16 * 16;
  constexpr int NBW = NB16 / 4;
  __shared__ float smF[32][FST];
  const int t = threadIdx.x;
  const int lane = t & 63;
  const int wv = t >> 6;
  const int m0 = blockIdx.x * 32;

  float* const base = &smF[wv * 8][0];
  const char* const Xc = (const char*)Xb;
  const int q = lane >> 4;                // 16-lane group id (0..3)
  const int li = lane & 15;
  const unsigned li16 = (unsigned)li * 16u;

  // prefetch the 9 row bounds for this wave's 8 rows
  int bnd = (lane < 9) ? rowoffG[blockIdx.x * 33 + wv * 8 + lane] : 0;

  #define LD4(r) (*(const u4*)(Xc + ((size_t)(r) << 8) + li16))
  #define ACC(v) { a0 += blo((v)[0]); a1 += bhi((v)[0]); a2 += blo((v)[1]); a3 += bhi((v)[1]); \
                   a4 += blo((v)[2]); a5 += bhi((v)[2]); a6 += blo((v)[3]); a7 += bhi((v)[3]); }

  #pragma unroll 1
  for (int r = 0; r < 8; ++r){
    int e   = __builtin_amdgcn_readfirstlane(__shfl(bnd, r));
    int end = __builtin_amdgcn_readfirstlane(__shfl(bnd, r + 1));
    float a0 = 0.f, a1 = 0.f, a2 = 0.f, a3 = 0.f;
    float a4 = 0.f, a5 = 0.f, a6 = 0.f, a7 = 0.f;
    // 16 edges per iter: 4 rec loads + 4 x4-gathers in flight
    while (e + 16 <= end){
      unsigned r0 = ss32[e + q];
      unsigned r1 = ss32[e + 4 + q];
      unsigned r2 = ss32[e + 8 + q];
      unsigned r3 = ss32[e + 12 + q];
      u4 v0 = LD4(r0);
      u4 v1 = LD4(r1);
      u4 v2 = LD4(r2);
      u4 v3 = LD4(r3);
      ACC(v0); ACC(v1); ACC(v2); ACC(v3);
      e += 16;
    }
    if (e + 8 <= end){
      unsigned r0 = ss32[e + q];
      unsigned r1 = ss32[e + 4 + q];
      u4 v0 = LD4(r0);
      u4 v1 = LD4(r1);
      ACC(v0); ACC(v1);
      e += 8;
    }
    // predicated tail: 1..7 edges, 4 at a time with clamp+mask
    while (e < end){
      int nv = end - e;                       // scalar
      int sel = (q < nv) ? q : (nv - 1);
      unsigned rr = ss32[e + sel];
      u4 v = LD4(rr);
      if (q >= nv){ v[0] = 0; v[1] = 0; v[2] = 0; v[3] = 0; }
      ACC(v);
      e += (nv < 4) ? nv : 4;
    }
    // fold the 4 group partials (lanes l, l+16, l+32, l+48 hold same dims)
    a0 += __shfl_xor(a0, 16); a1 += __shfl_xor(a1, 16);
    a2 += __shfl_xor(a2, 16); a3 += __shfl_xor(a3, 16);
    a4 += __shfl_xor(a4, 16); a5 += __shfl_xor(a5, 16);
    a6 += __shfl_xor(a6, 16); a7 += __shfl_xor(a7, 16);
    a0 += __shfl_xor(a0, 32); a1 += __shfl_xor(a1, 32);
    a2 += __shfl_xor(a2, 32); a3 += __shfl_xor(a3, 32);
    a4 += __shfl_xor(a4, 32); a5 += __shfl_xor(a5, 32);
    a6 += __shfl_xor(a6, 32); a7 += __shfl_xor(a7, 32);
    if (q == 0){
      float* p = base + r * FST + li * 8;
      f4 w0; w0[0] = a0; w0[1] = a1; w0[2] = a2; w0[3] = a3;
      f4 w1; w1[0] = a4; w1[1] = a5; w1[2] = a6; w1[3] = a7;
      *(f4*)p = w0;
      *(f4*)(p + 4) = w1;
    }
  }
  #undef LD4
  #undef ACC
  __syncthreads();

  // normalize (degree = rowoffG range width)
  {
    int row = t >> 3;                    // 0..31 within block
    int beg = rowoffG[blockIdx.x * 33 + row];
    int fin = rowoffG[blockIdx.x * 33 + row + 1];
    int d = fin - beg;
    float inv = (d > 0) ? 1.f / (float)d : 0.f;
    float* pr = &smF[row][(t & 7) * 16];
    #pragma unroll
    for (int i = 0; i < 16; ++i) pr[i] *= inv;
  }
  __syncthreads();

  // ---- phase 2: dual GEMM ----
  const int q2 = lane >> 4, lr = lane & 15;
  const short8* pb = (const short8*)Bp + lane;
  f4 acc[2][NBW];
  #pragma unroll
  for (int gg = 0; gg < 2; ++gg)
    #pragma unroll
    for (int j = 0; j < NBW; ++j)
      acc[gg][j] = (f4){0.f, 0.f, 0.f, 0.f};

  #pragma unroll
  for (int ks = 0; ks < 4; ++ks){
    const float* r0 = &smF[lr][ks * 32 + q2 * 8];
    const float* r1 = &smF[lr + 16][ks * 32 + q2 * 8];
    short8 a0 = cvt8(*(const f4*)r0, *(const f4*)(r0 + 4));
    short8 a1 = cvt8(*(const f4*)r1, *(const f4*)(r1 + 4));
    #pragma unroll
    for (int j = 0; j < NBW; ++j){
      int nb2 = wv * NBW + j;
      short8 b = pb[(ks * NB16 + nb2) * 64];
      acc[0][j] = __builtin_amdgcn_mfma_f32_16x16x32_bf16(a0, b, acc[0][j], 0, 0, 0);
      acc[1][j] = __builtin_amdgcn_mfma_f32_16x16x32_bf16(a1, b, acc[1][j], 0, 0, 0);
    }
  }
  #pragma unroll
  for (int ks = 0; ks < 4; ++ks){
    short8 a0 = *(const short8*)(Xb + (size_t)(m0 + lr) * 64 + q2*4 + ks*16);
    short8 a1 = *(const short8*)(Xb + (size_t)(m0 + lr + 16) * 64 + q2*4 + ks*16);
    #pragma unroll
    for (int j = 0; j < NBW; ++j){
      int nb2 = wv * NBW + j;
      short8 b = pb[((4 + ks) * NB16 + nb2) * 64];
      acc[0][j] = __builtin_amdgcn_mfma_f32_16x16x32_bf16(a0, b, acc[0][j], 0, 0, 0);
      acc[1][j] = __builtin_amdgcn_mfma_f32_16x16x32_bf16(a1, b, acc[1][j], 0, 0, 0);
    }
  }

  // ---- epilogue ----
  #pragma unroll
  for (int j = 0; j < NBW; ++j){
    int col = (wv * NBW + j) * 16 + lr;
    float S = 1.f, T;
    if constexpr (DO_BN){
      float s = bg[col] * rsqrtf(bv[col] + 1e-5f);
      S = s;
      T = (bias[col] - bm[col]) * s + bb[col];
    } else {
      T = bias[col];
    }
    #pragma unroll
    for (int r = 0; r < 4; ++r){
      int row = m0 + q2 * 4 + r;
      float y0 = acc[0][j][r] * S + T;
      float y1 = acc[1][j][r] * S + T;
      if constexpr (DO_BN){
        y0 = y0 > 0.f ? y0 : 0.f;
        y1 = y1 > 0.f ? y1 : 0.f;
        OutB[(size_t)row * DOUT + col] = f2bf(y0);
        OutB[(size_t)(row + 16) * DOUT + col] = f2bf(y1);
      } else {
        OutF[(size_t)row * DOUT + col] = y0;
        OutF[(size_t)(row + 16) * DOUT + col] = y1;
      }
    }
  }
}

extern "C" void kernel_launch(void* const* d_in, const int* in_sizes, int n_in,
                              void* d_out, int out_size, void* d_ws, size_t ws_size,
                              hipStream_t stream){
  const float* x = (const float*)d_in[0];
  const int* ei = (const int*)d_in[1];
  const float* Wl0 = (const float*)d_in[2];
  const float* Wr0 = (const float*)d_in[3];
  const float* bl0 = (const float*)d_in[4];
  const float* Wl1 = (const float*)d_in[5];
  const float* Wr1 = (const float*)d_in[6];
  const float* bl1 = (const float*)d_in[7];
  const float* Wl2 = (const float*)d_in[8];
  const float* Wr2 = (const float*)d_in[9];
  const float* bl2 = (const float*)d_in[10];
  const float* g0 = (const float*)d_in[11];
  const float* b0 = (const float*)d_in[12];
  const float* bm0 = (const float*)d_in[13];
  const float* bv0 = (const float*)d_in[14];
  const float* g1 = (const float*)d_in[15];
  const float* b1 = (const float*)d_in[16];
  const float* bm1 = (const float*)d_in[17];
  const float* bv1 = (const float*)d_in[18];

  const size_t REQUIRED = 51600000;
  if (ws_size < REQUIRED){
    k_sentinel<<<(out_size + 255) / 256, 256, 0, stream>>>((float*)d_out, out_size);
    return;
  }

  char* w = (char*)d_ws;
  size_t off = 0;
  auto alloc = [&](size_t bytes) -> char* {
    char* p = w + off; off = (off + bytes + 255) & ~(size_t)255; return p;
  };
  int* rowoffG = (int*)alloc((size_t)NGB * 33 * 4);
  unsigned* ss32 = (unsigned*)alloc((size_t)NE * 4);
  unsigned short* bp0 = (unsigned short*)alloc(8 * 8 * 64 * 8 * 2);
  unsigned short* bp1 = (unsigned short*)alloc(8 * 8 * 64 * 8 * 2);
  unsigned short* bp2 = (unsigned short*)alloc(8 * 4 * 64 * 8 * 2);
  unsigned* xb = (unsigned*)alloc((size_t)NN * 64 * 4);   // bf16x2 x; reused as h2
  unsigned short* h2 = (unsigned short*)xb;
  int* histT = (int*)alloc((size_t)LEN2 * 4);
  int* Bb   = (int*)alloc((size_t)(NGB + 1) * 4);
  int* bsum = (int*)alloc(NB_SCAN2 * 4);
  int* boff = (int*)alloc(NB_SCAN2 * 4);
  unsigned short* h1 = (unsigned short*)d_out;            // 25.6 MB, exactly d_out

  const int* srcI = ei;
  const int* dstI = ei + NE;

  k_cvt<<<(NN * 16 + 255) / 256, 256, 0, stream>>>(x, xb);
  k_hist<<<NBH, 256, 0, stream>>>(dstI, histT);
  k_bsum<<<NB_SCAN2, 256, 0, stream>>>(histT, bsum, LEN2);
  k_scanp<<<1, 256, 0, stream>>>(bsum, boff, NB_SCAN2);
  k_scanf2<<<NB_SCAN2, 256, 0, stream>>>(histT, boff, Bb, LEN2);
  k_scat<<<NBH, 256, 0, stream>>>(srcI, dstI, histT, ss32);
  k_scat2<<<NGB, 256, 0, stream>>>(ss32, Bb, rowoffG);
  k_packall<<<40, 256, 0, stream>>>(Wl0, Wr0, Wl1, Wr1, Wl2, Wr2, bp0, bp1, bp2);

  k_fused<8, true ><<<NGB, 256, 0, stream>>>(xb, rowoffG, ss32, bp0,
      bl0, g0, b0, bm0, bv0, h1, nullptr);
  k_fused<8, true ><<<NGB, 256, 0, stream>>>((const unsigned*)h1, rowoffG, ss32, bp1,
      bl1, g1, b1, bm1, bv1, h2, nullptr);
  k_fused<4, false><<<NGB, 256, 0, stream>>>((const unsigned*)h2, rowoffG, ss32, bp2,
      bl2, nullptr, nullptr, nullptr, nullptr, nullptr, (float*)d_out);
}